// Round 4
// baseline (370.006 us; speedup 1.0000x reference)
//
#include <hip/hip_runtime.h>

// Problem constants (fixed by the reference file)
#define BB 4096
#define FF 16384
#define GG 512
#define SS 32
#define HALF (FF / 2)   // 8192 floats = 32 KiB per row-half

typedef float v4f __attribute__((ext_vector_type(4)));

// v[idx[i]] = w[i] * fc[i>>5].
// group_idx is arange(G*S).reshape(G,S): a permutation covering 0..F-1
// exactly once (G*S == F). Plain scatter store, no memset, no atomics.
__global__ void build_v_kernel(const int* __restrict__ idx,
                               const float* __restrict__ w,
                               const float* __restrict__ fc,
                               float* __restrict__ v) {
    int i = blockIdx.x * blockDim.x + threadIdx.x;
    if (i < GG * SS) {
        v[idx[i]] = w[i] * fc[i >> 5];  // SS = 32
    }
}

// MEASUREMENT-PROBE GEMV (expected to REGRESS -- the delta is the data).
// Identical real math to the 337us variants (nt restored: round 3 proved
// nt is worth ~20us), PLUS a dummy second stream over the OPPOSITE
// row-half of x. This exactly doubles gemv HBM x-traffic. The dummy
// accumulator is kept alive via empty asm (rule: ablation-via-skip DCEs
// upstream ops -- same trick inverted), real outputs are bit-identical.
//   dur ~460-490 -> gemv really is capped at ~1.7 TB/s (structure-indep)
//   dur ~380-400 -> gemv is near its 43us HBM roofline; rest is fixed cost
//   dur ~340-355 -> gemv negligible; fixed costs dominate -> roofline
__global__ __launch_bounds__(256, 8) void gemv_kernel(const float* __restrict__ x,
                                                      const float* __restrict__ v,
                                                      float* __restrict__ part) {
    const int tid  = threadIdx.x;
    const int wave = tid >> 6;
    const int lane = tid & 63;
    const int h    = (blockIdx.x << 2) + wave;   // 0..8191
    const int row  = h >> 1;
    const int c    = h & 1;

    const v4f* __restrict__ x4 = (const v4f*)(x + (size_t)row * FF + c * HALF);
    const v4f* __restrict__ y4 = (const v4f*)(x + (size_t)row * FF + (c ^ 1) * HALF);
    const v4f* __restrict__ v4 = (const v4f*)(v + c * HALF);

    v4f a0 = {0.f, 0.f, 0.f, 0.f}, a1 = a0;   // real accumulators
    v4f b0 = a0, b1 = a0;                      // dummy accumulators
    // HALF/4 = 2048 v4f over 64 lanes, 2 per trip -> 16 trips; unroll 2
    // -> 8 real + 8 dummy x-loads in flight per lane.
    #pragma unroll 2
    for (int i = lane; i < HALF / 4; i += 128) {
        v4f xa0 = __builtin_nontemporal_load(&x4[i]);
        v4f xa1 = __builtin_nontemporal_load(&x4[i + 64]);
        v4f xb0 = __builtin_nontemporal_load(&y4[i]);       // dummy stream
        v4f xb1 = __builtin_nontemporal_load(&y4[i + 64]);  // dummy stream
        v4f vv0 = v4[i];
        v4f vv1 = v4[i + 64];
        a0 += xa0 * vv0;
        a1 += xa1 * vv1;
        b0 += xb0 * vv0;   // dead math, loads kept live below
        b1 += xb1 * vv1;
    }
    // keep the dummy stream alive without touching the real result
    v4f bsum = b0 + b1;
    float dummy = (bsum.x + bsum.y) + (bsum.z + bsum.w);
    asm volatile("" :: "v"(dummy));

    v4f acc = a0 + a1;
    float sum = (acc.x + acc.y) + (acc.z + acc.w);

    #pragma unroll
    for (int off = 32; off > 0; off >>= 1)
        sum += __shfl_down(sum, off, 64);

    if (lane == 0) part[c * BB + row] = sum;
}

// out[b] = part[0][b] + part[1][b]
__global__ void combine_kernel(const float* __restrict__ part,
                               float* __restrict__ out) {
    int i = blockIdx.x * blockDim.x + threadIdx.x;
    if (i < BB) out[i] = part[i] + part[BB + i];
}

extern "C" void kernel_launch(void* const* d_in, const int* in_sizes, int n_in,
                              void* d_out, int out_size, void* d_ws, size_t ws_size,
                              hipStream_t stream) {
    const float* x   = (const float*)d_in[0];   // (B, F) fp32
    const int*   idx = (const int*)d_in[1];     // (G, S) int
    const float* w   = (const float*)d_in[2];   // (G, S) fp32
    const float* fc  = (const float*)d_in[3];   // (G, 1) fp32
    float* out = (float*)d_out;                 // (B, 1) fp32
    float* v    = (float*)d_ws;                 // F fp32 scratch (64 KiB)
    float* part = v + FF;                       // 2*B fp32 partials (32 KiB)

    build_v_kernel<<<(GG * SS + 255) / 256, 256, 0, stream>>>(idx, w, fc, v);
    gemv_kernel<<<BB / 2, 256, 0, stream>>>(x, v, part);
    combine_kernel<<<(BB + 255) / 256, 256, 0, stream>>>(part, out);
}

// Round 5
// 341.554 us; speedup vs baseline: 1.0833x; 1.0833x over previous
//
#include <hip/hip_runtime.h>

// Problem constants (fixed by the reference file)
#define BB 4096
#define FF 16384
#define GG 512
#define SS 32
#define HALF (FF / 2)   // 8192 floats = 32 KiB per row-half

typedef float v4f __attribute__((ext_vector_type(4)));
typedef int   v4i __attribute__((ext_vector_type(4)));

// Raw buffer load with explicit cache policy. gfx940+/gfx950 CPol bits:
// bit0 = sc0, bit1 = nt, bit4 = sc1.  nt|sc1 = no-allocate (stream) --
// the load does not allocate in L2/MALL, so it cannot force eviction/
// writeback of the harness's dirty poison lines. Declared CK-style so
// the compiler still tracks the load for vmcnt insertion (no asm-waitcnt
// hazards, per methodology rule #18).
extern "C" __device__ v4f
llvm_amdgcn_raw_buffer_load_v4f32(v4i rsrc, int voffset, int soffset,
                                  int cachepolicy)
    __asm("llvm.amdgcn.raw.buffer.load.v4f32");

#define CPOL_NT_SC1 18  // nt(2) | sc1(16)

__device__ inline v4i make_srsrc(const void* p, int bytes) {
    union { const void* ptr; int i[2]; } a;
    a.ptr = p;
    v4i r;
    r.x = a.i[0];        // base[31:0]
    r.y = a.i[1];        // base[47:32], stride = 0
    r.z = bytes;         // num_records (bytes, since stride==0)
    r.w = 0x00020000;    // raw untyped dword access
    return r;
}

// v[idx[i]] = w[i] * fc[i>>5].
// group_idx is arange(G*S).reshape(G,S): a permutation covering 0..F-1
// exactly once (G*S == F). Plain scatter store, no memset, no atomics.
__global__ void build_v_kernel(const int* __restrict__ idx,
                               const float* __restrict__ w,
                               const float* __restrict__ fc,
                               float* __restrict__ v) {
    int i = blockIdx.x * blockDim.x + threadIdx.x;
    if (i < GG * SS) {
        v[idx[i]] = w[i] * fc[i >> 5];  // SS = 32
    }
}

// GEMV, round-2 structure (LDS-staged v: inner loop's VMEM queue holds
// ONLY x), with the x-load path swapped from flat global `nt` loads to
// buffer_load `nt sc1` (no-allocate). A/B vs round 2's 337us isolates
// exactly one mechanism: whether x allocations evicting the harness's
// dirty poison lines (forced writeback + R/W turnaround) is the ~1.8TB/s
// cap on this stream.
__global__ __launch_bounds__(256, 4) void gemv_kernel(const float* __restrict__ x,
                                                      const float* __restrict__ v,
                                                      float* __restrict__ part) {
    __shared__ v4f vs[HALF / 4];  // 2048 v4f = 32 KiB

    const int c   = blockIdx.x & 1;
    const int r0  = (blockIdx.x >> 1) << 2;
    const int tid = threadIdx.x;

    // cooperative LDS fill: 2048 v4f over 256 threads = 8 iters
    const v4f* __restrict__ vg = (const v4f*)(v + c * HALF);
    #pragma unroll
    for (int i = tid; i < HALF / 4; i += 256)
        vs[i] = vg[i];
    __syncthreads();

    const int wave = tid >> 6;
    const int lane = tid & 63;
    const int row  = r0 + wave;

    const v4i srsrc = make_srsrc(x + (size_t)row * FF + c * HALF, HALF * 4);

    v4f a0 = {0.f, 0.f, 0.f, 0.f}, a1 = a0;
    // HALF/4 = 2048 v4f over 64 lanes, 2 per trip -> 16 trips; unroll 4
    // -> 8 x-loads in flight per lane, only x in the vmcnt queue.
    #pragma unroll 4
    for (int i = lane; i < HALF / 4; i += 128) {
        v4f xa = llvm_amdgcn_raw_buffer_load_v4f32(srsrc, i * 16, 0, CPOL_NT_SC1);
        v4f xb = llvm_amdgcn_raw_buffer_load_v4f32(srsrc, (i + 64) * 16, 0, CPOL_NT_SC1);
        a0 += xa * vs[i];
        a1 += xb * vs[i + 64];
    }
    v4f acc = a0 + a1;
    float sum = (acc.x + acc.y) + (acc.z + acc.w);

    #pragma unroll
    for (int off = 32; off > 0; off >>= 1)
        sum += __shfl_down(sum, off, 64);

    if (lane == 0) part[c * BB + row] = sum;
}

// out[b] = part[0][b] + part[1][b]
__global__ void combine_kernel(const float* __restrict__ part,
                               float* __restrict__ out) {
    int i = blockIdx.x * blockDim.x + threadIdx.x;
    if (i < BB) out[i] = part[i] + part[BB + i];
}

extern "C" void kernel_launch(void* const* d_in, const int* in_sizes, int n_in,
                              void* d_out, int out_size, void* d_ws, size_t ws_size,
                              hipStream_t stream) {
    const float* x   = (const float*)d_in[0];   // (B, F) fp32
    const int*   idx = (const int*)d_in[1];     // (G, S) int
    const float* w   = (const float*)d_in[2];   // (G, S) fp32
    const float* fc  = (const float*)d_in[3];   // (G, 1) fp32
    float* out = (float*)d_out;                 // (B, 1) fp32
    float* v    = (float*)d_ws;                 // F fp32 scratch (64 KiB)
    float* part = v + FF;                       // 2*B fp32 partials (32 KiB)

    build_v_kernel<<<(GG * SS + 255) / 256, 256, 0, stream>>>(idx, w, fc, v);
    gemv_kernel<<<2 * (BB / 4), 256, 0, stream>>>(x, v, part);
    combine_kernel<<<(BB + 255) / 256, 256, 0, stream>>>(part, out);
}